// Round 2
// baseline (353.838 us; speedup 1.0000x reference)
//
#include <hip/hip_runtime.h>

typedef unsigned short u16;
typedef unsigned int   u32;
typedef short bf16x8 __attribute__((ext_vector_type(8)));
typedef float f32x4  __attribute__((ext_vector_type(4)));

__device__ __forceinline__ float bf2f(u16 u){
  union { u32 u; float f; } c; c.u = ((u32)u) << 16; return c.f;
}
__device__ __forceinline__ u16 f2bf(float f){
  union { float f; u32 u; } c; c.f = f;
  u32 u = c.u + 0x7fffu + ((c.u >> 16) & 1u);
  return (u16)(u >> 16);
}

// async global->LDS, 16B per lane; LDS dest must be wave-uniform base + lane*16
__device__ __forceinline__ void gload16(const u16* g, u16* l){
  __builtin_amdgcn_global_load_lds((const __attribute__((address_space(1))) u32*)g,
                                   (__attribute__((address_space(3))) u32*)l, 16, 0, 0);
}

// ---------------- reductions ----------------------------------------------
__device__ __forceinline__ float waveRed(float v, int ismax){
  #pragma unroll
  for (int o = 32; o > 0; o >>= 1){
    float t = __shfl_xor(v, o, 64);
    v = ismax ? fmaxf(v, t) : (v + t);
  }
  return v;
}
__device__ __forceinline__ float blockRed(float v, int ismax, float* red, int tid){
  v = waveRed(v, ismax);
  __syncthreads();
  if ((tid & 63) == 0) red[tid >> 6] = v;
  __syncthreads();
  return ismax ? fmaxf(fmaxf(red[0], red[1]), fmaxf(red[2], red[3]))
               : (red[0] + red[1] + red[2] + red[3]);
}

// ---------------- fused fp32 -> bf16 converter (x + 4 weights) -------------
__global__ __launch_bounds__(256)
void conv_all(const float* __restrict__ x, const float* __restrict__ w0,
              const float* __restrict__ w1, const float* __restrict__ w2,
              const float* __restrict__ w3, u16* __restrict__ xdst,
              u16* __restrict__ wdst){
  const int bid = blockIdx.x;
  const float* s;
  u16* d;
  size_t i;
  if (bid < 4096){
    s = x; d = xdst;
    i = ((size_t)bid * 256 + threadIdx.x) * 8;
  } else {
    const int wb = bid - 4096;
    const int wi = wb >> 9;
    s = wi == 0 ? w0 : (wi == 1 ? w1 : (wi == 2 ? w2 : w3));
    d = wdst + (size_t)wi * 1048576;
    i = ((size_t)(wb & 511) * 256 + threadIdx.x) * 8;
  }
  const float4 a = *(const float4*)(s + i);
  const float4 b = *(const float4*)(s + i + 4);
  uint4 o;
  o.x = (u32)f2bf(a.x) | ((u32)f2bf(a.y) << 16);
  o.y = (u32)f2bf(a.z) | ((u32)f2bf(a.w) << 16);
  o.z = (u32)f2bf(b.x) | ((u32)f2bf(b.y) << 16);
  o.w = (u32)f2bf(b.z) | ((u32)f2bf(b.w) << 16);
  *(uint4*)(d + i) = o;
}

// ---------------- diversity bias table: divp[b][s][t] ----------------------
__global__ __launch_bounds__(256)
void div_kernel(const float* __restrict__ pf, float* __restrict__ divp)
{
  __shared__ float pfs[64][129];
  __shared__ float svs[64][65];
  const int b = blockIdx.x;
  const int tid = threadIdx.x;
  const float* pb = pf + (size_t)b * 8192;
  for (int i = tid; i < 8192; i += 256) pfs[i >> 7][i & 127] = pb[i];
  __syncthreads();
  const int p = tid & 63, qg = tid >> 6;
  for (int qq = qg * 16; qq < qg * 16 + 16; ++qq){
    float a = 0.f;
    #pragma unroll 8
    for (int f = 0; f < 128; ++f) a += pfs[p][f] * pfs[qq][f];
    svs[p][qq] = a;
  }
  __syncthreads();
  if (tid < 64){
    float m = -1e30f;
    for (int qq = 0; qq < 64; ++qq) m = fmaxf(m, svs[tid][qq]);
    float s = 0.f;
    for (int qq = 0; qq < 64; ++qq){ const float e = __expf(svs[tid][qq] - m); svs[tid][qq] = e; s += e; }
    const float inv = 1.f / s;
    float* dr = divp + ((size_t)b * 64 + tid) * 64;
    for (int qq = 0; qq < 64; ++qq) dr[qq] = 0.1f * (1.f - svs[tid][qq] * inv);
  }
}

// ---------------- QKV GEMM: 256x256 tile, 8 waves, wave tile 128x64 --------
// Y = (A @ W^T + bias) * scale, A,W bf16 K-contiguous (K=1024), BK=32.
// 3-slot rotating LDS (96KB), distance-2 prefetch, counted vmcnt(4),
// both-sides XOR swizzle (conflict-free ds_read_b128, verified r1: 0 conflicts).
// Wave tile 128x64 -> 32 MFMA / 12 ds_read per wave-step (2.67 ratio vs 2.0).
// grid (32, 12): y -> wsel = y>>2 (Q/K/V), bn = y&3. Scatter bf16 (B,nh,S,dk).
__global__ __launch_bounds__(512, 2)
void gemm_qkv(const u16* __restrict__ A, const u16* __restrict__ Wb,
              const float* __restrict__ bias0, const float* __restrict__ bias1,
              const float* __restrict__ bias2, u16* __restrict__ outp)
{
  __shared__ u16 As[3][8192];      // 3 slots x [256 rows][32 cols] bf16, 16KB each
  __shared__ u16 Bs[3][8192];
  const int tid = threadIdx.x, lane = tid & 63, w = tid >> 6;
  const int wm = (w >> 2) * 128, wn = (w & 3) * 64;
  const int bm = blockIdx.x;
  const int y  = blockIdx.y;
  const int wsel = y >> 2, bn = y & 3;
  const u16* Wp = Wb + (size_t)wsel * 1048576;
  const float* bias = wsel == 0 ? bias0 : (wsel == 1 ? bias1 : bias2);
  const float scale = wsel == 0 ? 0.125f : 1.f;   // fold 1/sqrt(dk) into Q

  const f32x4 z = {0.f, 0.f, 0.f, 0.f};
  f32x4 acc[8][4];
  #pragma unroll
  for (int i = 0; i < 8; ++i)
    #pragma unroll
    for (int j = 0; j < 4; ++j) acc[i][j] = z;

  // staging: 16 chunks of 1KB per slot per matrix; wave w owns chunks 2w, 2w+1.
  // chunk ca covers rows [ca*16, ca*16+16); lane i -> row ca*16+i/4,
  // physical 16B-block i&3; source col PRE-SWIZZLED (r1-verified layout).
  const int r4  = lane >> 2;
  const int c8s = (((lane & 3) ^ ((lane >> 3) & 3)) * 8);
  const int ca0 = w * 2, ca1 = w * 2 + 1;
  const u16* gA0 = A  + (size_t)(bm * 256 + ca0 * 16 + r4) * 1024 + c8s;
  const u16* gA1 = A  + (size_t)(bm * 256 + ca1 * 16 + r4) * 1024 + c8s;
  const u16* gB0 = Wp + (size_t)(bn * 256 + ca0 * 16 + r4) * 1024 + c8s;
  const u16* gB1 = Wp + (size_t)(bn * 256 + ca1 * 16 + r4) * 1024 + c8s;
  const int lo0 = ca0 * 512 + lane * 8;     // u16 offset within slot
  const int lo1 = ca1 * 512 + lane * 8;

  // frag reads: logical (row, kblock=quad) -> physical block quad^((row>>1)&3)
  const int fr = lane & 15, quad = lane >> 4;
  int offA[8], offB[4];
  #pragma unroll
  for (int i = 0; i < 8; ++i){
    const int r = wm + i * 16 + fr;
    offA[i] = r * 32 + ((quad ^ ((r >> 1) & 3)) * 8);
  }
  #pragma unroll
  for (int j = 0; j < 4; ++j){
    const int r = wn + j * 16 + fr;
    offB[j] = r * 32 + ((quad ^ ((r >> 1) & 3)) * 8);
  }

#define STG(s, kk) \
    gload16(gA0 + (kk), &As[s][lo0]); \
    gload16(gA1 + (kk), &As[s][lo1]); \
    gload16(gB0 + (kk), &Bs[s][lo0]); \
    gload16(gB1 + (kk), &Bs[s][lo1]);

  // prologue: tiles 0,1 staged; wait tile 0 (4 newest = tile 1 stay in flight)
  STG(0, 0)
  STG(1, 32)
  asm volatile("s_waitcnt vmcnt(4)" ::: "memory");
  __builtin_amdgcn_sched_barrier(0);
  __builtin_amdgcn_s_barrier();
  asm volatile("" ::: "memory");
  __builtin_amdgcn_sched_barrier(0);

  int slot = 0;
  #pragma unroll 1
  for (int t = 0; t < 32; ++t){
    const int s2 = slot < 1 ? 2 : slot - 1;          // (slot+2)%3
    if (t < 30){ STG(s2, (t + 2) * 32) }             // prefetch tile t+2
    const u16* as_ = As[slot];
    const u16* bs_ = Bs[slot];
    bf16x8 af[8], bfv[4];
    #pragma unroll
    for (int i = 0; i < 8; ++i) af[i]  = *(const bf16x8*)&as_[offA[i]];
    #pragma unroll
    for (int j = 0; j < 4; ++j) bfv[j] = *(const bf16x8*)&bs_[offB[j]];
    __builtin_amdgcn_s_setprio(1);
    #pragma unroll
    for (int i = 0; i < 8; ++i)
      #pragma unroll
      for (int j = 0; j < 4; ++j)
        acc[i][j] = __builtin_amdgcn_mfma_f32_16x16x32_bf16(af[i], bfv[j], acc[i][j], 0, 0, 0);
    __builtin_amdgcn_s_setprio(0);
    // end-of-iter: ensure tile t+1 landed; keep this iter's 4 loads in flight
    if (t < 30)       { asm volatile("s_waitcnt vmcnt(4)" ::: "memory"); }
    else if (t == 30) { asm volatile("s_waitcnt vmcnt(0)" ::: "memory"); }
    if (t < 31){
      __builtin_amdgcn_sched_barrier(0);
      __builtin_amdgcn_s_barrier();
      asm volatile("" ::: "memory");
      __builtin_amdgcn_sched_barrier(0);
    }
    slot = slot == 2 ? 0 : slot + 1;
  }
#undef STG

  // D layout: row = (lane>>4)*4 + r, col = lane&15 (m89-verified)
  #pragma unroll
  for (int i = 0; i < 8; ++i){
    #pragma unroll
    for (int j = 0; j < 4; ++j){
      const int gr0 = bm * 256 + wm + i * 16 + quad * 4;
      const int gc  = bn * 256 + wn + j * 16 + fr;
      const float bvv = bias[gc];
      #pragma unroll
      for (int r = 0; r < 4; ++r){
        const int gr = gr0 + r;
        const float val = (acc[i][j][r] + bvv) * scale;
        const int b = gr >> 8, s = gr & 255, h = gc >> 6, kk = gc & 63;
        outp[(size_t)wsel * 8388608 + (size_t)b * 262144 +
             (size_t)h * 16384 + (size_t)s * 64 + kk] = f2bf(val);
      }
    }
  }
}

// ---------------- out-proj GEMM: r1-verified 128x128 3-slot pipeline -------
// (kept exactly as round-1 MODE 1: 512 small blocks fully resident beats
//  128 big blocks on a 256-CU chip for this 1/3-size GEMM)
template<int MODE>
__global__ __launch_bounds__(256, 3)
void gemm_lds(const u16* __restrict__ A, const u16* __restrict__ Wb,
              const float* __restrict__ bias0, const float* __restrict__ bias1,
              const float* __restrict__ bias2, void* __restrict__ outp)
{
  __shared__ u16 As[3][4096];
  __shared__ u16 Bs[3][4096];
  const int tid = threadIdx.x, lane = tid & 63, w = tid >> 6;
  const int wm = (w >> 1) * 64, wn = (w & 1) * 64;
  const int bm = blockIdx.x;
  int bn = blockIdx.y;
  const u16* Wp = Wb;
  const float* bias = bias0;
  float scale = 1.f;
  int wsel = 0;
  if (MODE == 0){
    wsel = bn >> 3; bn &= 7;
    Wp = Wb + (size_t)wsel * 1048576;
    bias = wsel == 0 ? bias0 : (wsel == 1 ? bias1 : bias2);
    if (wsel == 0) scale = 0.125f;
  }

  const f32x4 z = {0.f, 0.f, 0.f, 0.f};
  f32x4 acc[4][4];
  #pragma unroll
  for (int i = 0; i < 4; ++i)
    #pragma unroll
    for (int j = 0; j < 4; ++j) acc[i][j] = z;

  const int r4  = lane >> 2;
  const int c8s = (((lane & 3) ^ ((lane >> 3) & 3)) * 8);
  const int ca0 = w * 2, ca1 = w * 2 + 1;
  const u16* gA0 = A  + (size_t)(bm * 128 + ca0 * 16 + r4) * 1024 + c8s;
  const u16* gA1 = A  + (size_t)(bm * 128 + ca1 * 16 + r4) * 1024 + c8s;
  const u16* gB0 = Wp + (size_t)(bn * 128 + ca0 * 16 + r4) * 1024 + c8s;
  const u16* gB1 = Wp + (size_t)(bn * 128 + ca1 * 16 + r4) * 1024 + c8s;
  const int lo0 = ca0 * 512 + lane * 8;
  const int lo1 = ca1 * 512 + lane * 8;

  const int fr = lane & 15, quad = lane >> 4;
  int offA[4], offB[4];
  #pragma unroll
  for (int i = 0; i < 4; ++i){
    const int r = wm + i * 16 + fr;
    offA[i] = r * 32 + ((quad ^ ((r >> 1) & 3)) * 8);
  }
  #pragma unroll
  for (int j = 0; j < 4; ++j){
    const int r = wn + j * 16 + fr;
    offB[j] = r * 32 + ((quad ^ ((r >> 1) & 3)) * 8);
  }

#define STG(s, kk) \
    gload16(gA0 + (kk), &As[s][lo0]); \
    gload16(gA1 + (kk), &As[s][lo1]); \
    gload16(gB0 + (kk), &Bs[s][lo0]); \
    gload16(gB1 + (kk), &Bs[s][lo1]);

  STG(0, 0)
  STG(1, 32)
  asm volatile("s_waitcnt vmcnt(4)" ::: "memory");
  __builtin_amdgcn_sched_barrier(0);
  __builtin_amdgcn_s_barrier();
  asm volatile("" ::: "memory");
  __builtin_amdgcn_sched_barrier(0);

  int slot = 0;
  #pragma unroll 1
  for (int t = 0; t < 32; ++t){
    const int s2 = slot < 1 ? 2 : slot - 1;
    if (t < 30){ STG(s2, (t + 2) * 32) }
    const u16* as_ = As[slot];
    const u16* bs_ = Bs[slot];
    bf16x8 af[4], bfv[4];
    #pragma unroll
    for (int i = 0; i < 4; ++i) af[i]  = *(const bf16x8*)&as_[offA[i]];
    #pragma unroll
    for (int j = 0; j < 4; ++j) bfv[j] = *(const bf16x8*)&bs_[offB[j]];
    __builtin_amdgcn_s_setprio(1);
    #pragma unroll
    for (int i = 0; i < 4; ++i)
      #pragma unroll
      for (int j = 0; j < 4; ++j)
        acc[i][j] = __builtin_amdgcn_mfma_f32_16x16x32_bf16(af[i], bfv[j], acc[i][j], 0, 0, 0);
    __builtin_amdgcn_s_setprio(0);
    if (t < 30)       { asm volatile("s_waitcnt vmcnt(4)" ::: "memory"); }
    else if (t == 30) { asm volatile("s_waitcnt vmcnt(0)" ::: "memory"); }
    if (t < 31){
      __builtin_amdgcn_sched_barrier(0);
      __builtin_amdgcn_s_barrier();
      asm volatile("" ::: "memory");
      __builtin_amdgcn_sched_barrier(0);
    }
    slot = slot == 2 ? 0 : slot + 1;
  }
#undef STG

  #pragma unroll
  for (int i = 0; i < 4; ++i){
    #pragma unroll
    for (int j = 0; j < 4; ++j){
      const int gr0 = bm * 128 + wm + i * 16 + ((lane >> 4) * 4);
      const int gc  = bn * 128 + wn + j * 16 + (lane & 15);
      const float bvv = bias[gc];
      #pragma unroll
      for (int r = 0; r < 4; ++r){
        const int gr = gr0 + r;
        const float val = (acc[i][j][r] + bvv) * scale;
        if (MODE == 0){
          const int b = gr >> 8, s = gr & 255, h = gc >> 6, kk = gc & 63;
          ((u16*)outp)[(size_t)wsel * 8388608 + (size_t)b * 262144 +
                       (size_t)h * 16384 + (size_t)s * 64 + kk] = f2bf(val);
        } else {
          ((float*)outp)[(size_t)gr * 1024 + gc] = val;
        }
      }
    }
  }
}

// ---------------- MFMA attention: block per (b,h) --------------------------
__global__ __launch_bounds__(256)
void attn_mfma(const u16* __restrict__ q, const u16* __restrict__ k,
               const u16* __restrict__ v, const float* __restrict__ divp,
               u16* __restrict__ attn_s)
{
  __shared__ u16 Vt[64][264];
  __shared__ u16 Ps[4][16][136];
  const int bh = blockIdx.x;
  const int b = bh >> 4, h = bh & 15;
  const int tid = threadIdx.x, lane = tid & 63, w = tid >> 6;
  const int quad = lane >> 4, l15 = lane & 15;
  const u16* kh = k + (size_t)bh * 16384;
  const u16* vh = v + (size_t)bh * 16384;
  const u16* qh = q + (size_t)bh * 16384;

  #pragma unroll
  for (int c = 0; c < 4; ++c){
    const int pidx = tid + c * 256;
    const int t2 = pidx & 127;
    const int n0 = (pidx >> 7) * 8;
    const uint4 a  = *(const uint4*)(vh + (2 * t2) * 64 + n0);
    const uint4 bb = *(const uint4*)(vh + (2 * t2 + 1) * 64 + n0);
    const u32 aa[4] = {a.x, a.y, a.z, a.w};
    const u32 bb4[4] = {bb.x, bb.y, bb.z, bb.w};
    #pragma unroll
    for (int j2 = 0; j2 < 4; ++j2){
      const u32 lo = aa[j2], hi = bb4[j2];
      *(u32*)&Vt[n0 + 2 * j2    ][2 * t2] = (lo & 0xffffu) | (hi << 16);
      *(u32*)&Vt[n0 + 2 * j2 + 1][2 * t2] = (lo >> 16) | (hi & 0xffff0000u);
    }
  }
  __syncthreads();

  const f32x4 z = {0.f, 0.f, 0.f, 0.f};
  const int bp = 2 * h + (b >> 4);
  for (int i = 0; i < 4; ++i){
    const int row0 = w * 64 + i * 16;
    const bf16x8 af0 = *(const bf16x8*)(qh + (size_t)(row0 + l15) * 64 + quad * 8);
    const bf16x8 af1 = *(const bf16x8*)(qh + (size_t)(row0 + l15) * 64 + 32 + quad * 8);
    f32x4 sc[16];
    #pragma unroll
    for (int ct = 0; ct < 16; ++ct){
      const bf16x8 b0 = *(const bf16x8*)(kh + (size_t)(ct * 16 + l15) * 64 + quad * 8);
      const bf16x8 b1 = *(const bf16x8*)(kh + (size_t)(ct * 16 + l15) * 64 + 32 + quad * 8);
      f32x4 a = __builtin_amdgcn_mfma_f32_16x16x32_bf16(af0, b0, z, 0, 0, 0);
      sc[ct]  = __builtin_amdgcn_mfma_f32_16x16x32_bf16(af1, b1, a, 0, 0, 0);
    }
    if (w == 0){
      const float* dv = divp + (size_t)b * 4096 + (size_t)(i * 16 + quad * 4) * 64 + l15;
      #pragma unroll
      for (int ct = 0; ct < 4; ++ct)
        #pragma unroll
        for (int rr = 0; rr < 4; ++rr)
          sc[ct][rr] += dv[rr * 64 + ct * 16];
    }
    float rs[4];
    #pragma unroll
    for (int rr = 0; rr < 4; ++rr){
      float m = sc[0][rr];
      #pragma unroll
      for (int ct = 1; ct < 16; ++ct) m = fmaxf(m, sc[ct][rr]);
      #pragma unroll
      for (int o = 1; o < 16; o <<= 1) m = fmaxf(m, __shfl_xor(m, o, 64));
      float s = 0.f;
      #pragma unroll
      for (int ct = 0; ct < 16; ++ct){
        const float e = __expf(sc[ct][rr] - m); sc[ct][rr] = e; s += e;
      }
      #pragma unroll
      for (int o = 1; o < 16; o <<= 1) s += __shfl_xor(s, o, 64);
      rs[rr] = 1.f / s;
    }
    f32x4 o4[4] = {z, z, z, z};
    #pragma unroll
    for (int half = 0; half < 2; ++half){
      #pragma unroll
      for (int ct = 0; ct < 8; ++ct)
        #pragma unroll
        for (int rr = 0; rr < 4; ++rr)
          Ps[w][quad * 4 + rr][ct * 16 + l15] = f2bf(sc[half * 8 + ct][rr] * rs[rr]);
      #pragma unroll
      for (int kc = 0; kc < 4; ++kc){
        const bf16x8 pa = *(const bf16x8*)&Ps[w][l15][kc * 32 + quad * 8];
        #pragma unroll
        for (int nt = 0; nt < 4; ++nt){
          const bf16x8 vb8 = *(const bf16x8*)&Vt[nt * 16 + l15][half * 128 + kc * 32 + quad * 8];
          o4[nt] = __builtin_amdgcn_mfma_f32_16x16x32_bf16(pa, vb8, o4[nt], 0, 0, 0);
        }
      }
    }
    const int sp = (b & 15) * 16 + (w * 4 + i);
    #pragma unroll
    for (int nt = 0; nt < 4; ++nt)
      #pragma unroll
      for (int rr = 0; rr < 4; ++rr){
        const int slo = quad * 4 + rr;
        const int cp = slo * 64 + nt * 16 + l15;
        attn_s[((size_t)bp * 256 + sp) * 1024 + cp] = f2bf(o4[nt][rr]);
      }
  }
}

// ---------------- attention_weights: mean over heads -----------------------
__global__ __launch_bounds__(256)
void aw_kernel(const u16* __restrict__ q, const u16* __restrict__ k,
               float* __restrict__ aw)
{
  __shared__ float redm[16][4];
  __shared__ float reds[16][4];
  const int blk = blockIdx.x;
  const int b = blk >> 4, st = blk & 15;
  const int tid = threadIdx.x, lane = tid & 63, w = tid >> 6;
  const int quad = lane >> 4, l15 = lane & 15;
  const int rowb = st * 16;
  const f32x4 z = {0.f, 0.f, 0.f, 0.f};
  float awacc[4][4] = {};
  for (int h = 0; h < 16; ++h){
    const u16* kh = k + (((size_t)b * 16 + h) * 16384);
    const u16* qh = q + (((size_t)b * 16 + h) * 16384);
    const bf16x8 af0 = *(const bf16x8*)(qh + (size_t)(rowb + l15) * 64 + quad * 8);
    const bf16x8 af1 = *(const bf16x8*)(qh + (size_t)(rowb + l15) * 64 + 32 + quad * 8);
    f32x4 sc[4];
    #pragma unroll
    for (int j4 = 0; j4 < 4; ++j4){
      const int ct = w * 4 + j4;
      const bf16x8 b0 = *(const bf16x8*)(kh + (size_t)(ct * 16 + l15) * 64 + quad * 8);
      const bf16x8 b1 = *(const bf16x8*)(kh + (size_t)(ct * 16 + l15) * 64 + 32 + quad * 8);
      f32x4 a = __builtin_amdgcn_mfma_f32_16x16x32_bf16(af0, b0, z, 0, 0, 0);
      sc[j4]  = __builtin_amdgcn_mfma_f32_16x16x32_bf16(af1, b1, a, 0, 0, 0);
    }
    float pm[4];
    #pragma unroll
    for (int rr = 0; rr < 4; ++rr){
      float m = fmaxf(fmaxf(sc[0][rr], sc[1][rr]), fmaxf(sc[2][rr], sc[3][rr]));
      #pragma unroll
      for (int o = 1; o < 16; o <<= 1) m = fmaxf(m, __shfl_xor(m, o, 64));
      pm[rr] = m;
    }
    if (l15 == 0)
      #pragma unroll
      for (int rr = 0; rr < 4; ++rr) redm[quad * 4 + rr][w] = pm[rr];
    __syncthreads();
    float ps[4];
    #pragma unroll
    for (int rr = 0; rr < 4; ++rr){
      const int row = quad * 4 + rr;
      const float m = fmaxf(fmaxf(redm[row][0], redm[row][1]),
                            fmaxf(redm[row][2], redm[row][3]));
      float s = 0.f;
      #pragma unroll
      for (int j4 = 0; j4 < 4; ++j4){
        const float e = __expf(sc[j4][rr] - m); sc[j4][rr] = e; s += e;
      }
      #pragma unroll
      for (int o = 1; o < 16; o <<= 1) s += __shfl_xor(s, o, 64);
      ps[rr] = s;
    }
    if (l15 == 0)
      #pragma unroll
      for (int rr = 0; rr < 4; ++rr) reds[quad * 4 + rr][w] = ps[rr];
    __syncthreads();
    #pragma unroll
    for (int rr = 0; rr < 4; ++rr){
      const int row = quad * 4 + rr;
      const float inv = 1.f / (reds[row][0] + reds[row][1] + reds[row][2] + reds[row][3]);
      #pragma unroll
      for (int j4 = 0; j4 < 4; ++j4) awacc[j4][rr] += sc[j4][rr] * inv;
    }
  }
  const size_t base = (size_t)b * 65536;
  #pragma unroll
  for (int j4 = 0; j4 < 4; ++j4){
    const int col = (w * 4 + j4) * 16 + l15;
    #pragma unroll
    for (int rr = 0; rr < 4; ++rr){
      const int row = rowb + quad * 4 + rr;
      aw[base + (size_t)row * 256 + col] = awacc[j4][rr] * 0.0625f;
    }
  }
}

// ---------------- residual + layernorm epilogue (fp32) ---------------------
__global__ __launch_bounds__(256)
void ln_kernel(const float* __restrict__ y2, const float* __restrict__ x,
               const float* __restrict__ g, const float* __restrict__ bb,
               float* __restrict__ outp)
{
  __shared__ float red[4];
  const int r = blockIdx.x, tid = threadIdx.x;
  const float4 yv = ((const float4*)(y2 + (size_t)r * 1024))[tid];
  const float4 xv = ((const float4*)(x  + (size_t)r * 1024))[tid];
  const float v0 = yv.x + xv.x;
  const float v1 = yv.y + xv.y;
  const float v2 = yv.z + xv.z;
  const float v3 = yv.w + xv.w;
  const float ssum = blockRed(v0 + v1 + v2 + v3, 0, red, tid);
  const float mu = ssum * (1.f / 1024.f);
  const float d0 = v0 - mu, d1 = v1 - mu, d2 = v2 - mu, d3 = v3 - mu;
  const float sq = blockRed(d0 * d0 + d1 * d1 + d2 * d2 + d3 * d3, 0, red, tid);
  const float rstd = rsqrtf(sq * (1.f / 1024.f) + 1e-5f);
  const float4 gv = ((const float4*)g)[tid];
  const float4 bv = ((const float4*)bb)[tid];
  float4 o;
  o.x = d0 * rstd * gv.x + bv.x;
  o.y = d1 * rstd * gv.y + bv.y;
  o.z = d2 * rstd * gv.z + bv.z;
  o.w = d3 * rstd * gv.w + bv.w;
  ((float4*)(outp + (size_t)r * 1024))[tid] = o;
}

extern "C" void kernel_launch(void* const* d_in, const int* in_sizes, int n_in,
                              void* d_out, int out_size, void* d_ws, size_t ws_size,
                              hipStream_t stream)
{
  int ix = -1, ipf = -1, iw[4] = {-1,-1,-1,-1}, iv[6] = {-1,-1,-1,-1,-1,-1};
  int nw = 0, nv = 0;
  for (int i = 0; i < n_in; ++i){
    const int sz = in_sizes[i];
    if (sz == 8388608 && ix < 0) ix = i;
    else if (sz == 262144 && ipf < 0) ipf = i;
    else if (sz == 1048576 && nw < 4) iw[nw++] = i;
    else if (sz == 1024 && nv < 6) iv[nv++] = i;
  }
  if (ix < 0 || ipf < 0 || nw != 4 || nv != 6){
    ix = 0; ipf = 1; iw[0] = 2; iv[0] = 3; iw[1] = 4; iv[1] = 5;
    iw[2] = 6; iv[2] = 7; iw[3] = 8; iv[3] = 9; iv[4] = 10; iv[5] = 11;
  }

  const float* x   = (const float*)d_in[ix];
  const float* pf  = (const float*)d_in[ipf];
  const float* wq  = (const float*)d_in[iw[0]];
  const float* wk  = (const float*)d_in[iw[1]];
  const float* wv  = (const float*)d_in[iw[2]];
  const float* wo  = (const float*)d_in[iw[3]];
  const float* bq  = (const float*)d_in[iv[0]];
  const float* bk  = (const float*)d_in[iv[1]];
  const float* bv  = (const float*)d_in[iv[2]];
  const float* bo  = (const float*)d_in[iv[3]];
  const float* lng = (const float*)d_in[iv[4]];
  const float* lnb = (const float*)d_in[iv[5]];

  float* out0   = (float*)d_out;            // final (B,H,W,d) fp32
  float* aw_out = out0 + 8388608;           // (B,S,S) fp32

  // d_out staging (dead before ln_kernel writes out0):
  //   [0, 16.78M)      x_bf bf16 (consumed by QKV gemm)
  //   [16.78M, 33.55M) attn scrambled bf16 (consumed by out-proj gemm)
  u16* x_bf = (u16*)d_out;
  u16* attn = x_bf + 8388608;
  // ws: qkv bf16 [0,48M); divp @48M (0.5M); W bf16 arena @49M (8MB);
  // y2 fp32 (32MB) aliases qkv after attention.
  u16* qkv    = (u16*)d_ws;
  float* divp = (float*)((char*)d_ws + (size_t)48 * 1048576);
  u16* warena = (u16*)((char*)d_ws + (size_t)49 * 1048576);
  float* y2   = (float*)d_ws;

  conv_all<<<6144, 256, 0, stream>>>(x, wq, wk, wv, wo, x_bf, warena);
  div_kernel<<<32, 256, 0, stream>>>(pf, divp);

  gemm_qkv<<<dim3(32, 12), 512, 0, stream>>>(x_bf, warena, bq, bk, bv, qkv);

  u16* qw = qkv, *kw = qkv + 8388608, *vw = qkv + 16777216;
  attn_mfma<<<512, 256, 0, stream>>>(qw, kw, vw, divp, attn);
  aw_kernel<<<512, 256, 0, stream>>>(qw, kw, aw_out);

  gemm_lds<1><<<dim3(64, 8), 256, 0, stream>>>(attn, warena + 3145728, bo, nullptr, nullptr, (void*)y2);
  ln_kernel<<<8192, 256, 0, stream>>>(y2, x, lng, lnb, out0);
}

// Round 3
// 339.065 us; speedup vs baseline: 1.0436x; 1.0436x over previous
//
#include <hip/hip_runtime.h>

typedef unsigned short u16;
typedef unsigned int   u32;
typedef short bf16x8 __attribute__((ext_vector_type(8)));
typedef float f32x4  __attribute__((ext_vector_type(4)));

__device__ __forceinline__ float bf2f(u16 u){
  union { u32 u; float f; } c; c.u = ((u32)u) << 16; return c.f;
}
__device__ __forceinline__ u16 f2bf(float f){
  union { float f; u32 u; } c; c.f = f;
  u32 u = c.u + 0x7fffu + ((c.u >> 16) & 1u);
  return (u16)(u >> 16);
}

// async global->LDS, 16B per lane; LDS dest must be wave-uniform base + lane*16
__device__ __forceinline__ void gload16(const u16* g, u16* l){
  __builtin_amdgcn_global_load_lds((const __attribute__((address_space(1))) u32*)g,
                                   (__attribute__((address_space(3))) u32*)l, 16, 0, 0);
}

// ---------------- reductions ----------------------------------------------
__device__ __forceinline__ float waveRed(float v, int ismax){
  #pragma unroll
  for (int o = 32; o > 0; o >>= 1){
    float t = __shfl_xor(v, o, 64);
    v = ismax ? fmaxf(v, t) : (v + t);
  }
  return v;
}
__device__ __forceinline__ float blockRed(float v, int ismax, float* red, int tid){
  v = waveRed(v, ismax);
  __syncthreads();
  if ((tid & 63) == 0) red[tid >> 6] = v;
  __syncthreads();
  return ismax ? fmaxf(fmaxf(red[0], red[1]), fmaxf(red[2], red[3]))
               : (red[0] + red[1] + red[2] + red[3]);
}

// ---------------- fused fp32 -> bf16 converter (x + 4 weights) -------------
__global__ __launch_bounds__(256)
void conv_all(const float* __restrict__ x, const float* __restrict__ w0,
              const float* __restrict__ w1, const float* __restrict__ w2,
              const float* __restrict__ w3, u16* __restrict__ xdst,
              u16* __restrict__ wdst){
  const int bid = blockIdx.x;
  const float* s;
  u16* d;
  size_t i;
  if (bid < 4096){
    s = x; d = xdst;
    i = ((size_t)bid * 256 + threadIdx.x) * 8;
  } else {
    const int wb = bid - 4096;
    const int wi = wb >> 9;
    s = wi == 0 ? w0 : (wi == 1 ? w1 : (wi == 2 ? w2 : w3));
    d = wdst + (size_t)wi * 1048576;
    i = ((size_t)(wb & 511) * 256 + threadIdx.x) * 8;
  }
  const float4 a = *(const float4*)(s + i);
  const float4 b = *(const float4*)(s + i + 4);
  uint4 o;
  o.x = (u32)f2bf(a.x) | ((u32)f2bf(a.y) << 16);
  o.y = (u32)f2bf(a.z) | ((u32)f2bf(a.w) << 16);
  o.z = (u32)f2bf(b.x) | ((u32)f2bf(b.y) << 16);
  o.w = (u32)f2bf(b.z) | ((u32)f2bf(b.w) << 16);
  *(uint4*)(d + i) = o;
}

// ---------------- diversity bias table: divp[b][s][t] ----------------------
__global__ __launch_bounds__(256)
void div_kernel(const float* __restrict__ pf, float* __restrict__ divp)
{
  __shared__ float pfs[64][129];
  __shared__ float svs[64][65];
  const int b = blockIdx.x;
  const int tid = threadIdx.x;
  const float* pb = pf + (size_t)b * 8192;
  for (int i = tid; i < 8192; i += 256) pfs[i >> 7][i & 127] = pb[i];
  __syncthreads();
  const int p = tid & 63, qg = tid >> 6;
  for (int qq = qg * 16; qq < qg * 16 + 16; ++qq){
    float a = 0.f;
    #pragma unroll 8
    for (int f = 0; f < 128; ++f) a += pfs[p][f] * pfs[qq][f];
    svs[p][qq] = a;
  }
  __syncthreads();
  if (tid < 64){
    float m = -1e30f;
    for (int qq = 0; qq < 64; ++qq) m = fmaxf(m, svs[tid][qq]);
    float s = 0.f;
    for (int qq = 0; qq < 64; ++qq){ const float e = __expf(svs[tid][qq] - m); svs[tid][qq] = e; s += e; }
    const float inv = 1.f / s;
    float* dr = divp + ((size_t)b * 64 + tid) * 64;
    for (int qq = 0; qq < 64; ++qq) dr[qq] = 0.1f * (1.f - svs[tid][qq] * inv);
  }
}

// ---------------- 128x128 MFMA GEMM (round-1 verified: 70.5us, 0 conflicts)
// Y = (A @ W^T + bias) * scale, A,W bf16 K-contiguous (K=1024), BK=32.
// 3-slot rotating LDS, distance-2 prefetch, counted vmcnt(4), XOR swizzle.
// MODE 0: fused QKV (grid y 0..23, wsel=y>>3). Q,K scatter (B,nh,S,dk);
//         V scatters TRANSPOSED (B,nh,dk,S) so attention PV needs no
//         LDS transpose (reads V^T fragments straight from global).
// MODE 1: out-proj, fp32 row-major out.
template<int MODE>
__global__ __launch_bounds__(256, 3)
void gemm_lds(const u16* __restrict__ A, const u16* __restrict__ Wb,
              const float* __restrict__ bias0, const float* __restrict__ bias1,
              const float* __restrict__ bias2, void* __restrict__ outp)
{
  __shared__ u16 As[3][4096];
  __shared__ u16 Bs[3][4096];
  const int tid = threadIdx.x, lane = tid & 63, w = tid >> 6;
  const int wm = (w >> 1) * 64, wn = (w & 1) * 64;
  const int bm = blockIdx.x;
  int bn = blockIdx.y;
  const u16* Wp = Wb;
  const float* bias = bias0;
  float scale = 1.f;
  int wsel = 0;
  if (MODE == 0){
    wsel = bn >> 3; bn &= 7;
    Wp = Wb + (size_t)wsel * 1048576;
    bias = wsel == 0 ? bias0 : (wsel == 1 ? bias1 : bias2);
    if (wsel == 0) scale = 0.125f;      // fold 1/sqrt(dk) into Q
  }

  const f32x4 z = {0.f, 0.f, 0.f, 0.f};
  f32x4 acc[4][4];
  #pragma unroll
  for (int i = 0; i < 4; ++i)
    #pragma unroll
    for (int j = 0; j < 4; ++j) acc[i][j] = z;

  const int r4  = lane >> 2;
  const int c8s = (((lane & 3) ^ ((lane >> 3) & 3)) * 8);
  const int ca0 = w * 2, ca1 = w * 2 + 1;
  const u16* gA0 = A  + (size_t)(bm * 128 + ca0 * 16 + r4) * 1024 + c8s;
  const u16* gA1 = A  + (size_t)(bm * 128 + ca1 * 16 + r4) * 1024 + c8s;
  const u16* gB0 = Wp + (size_t)(bn * 128 + ca0 * 16 + r4) * 1024 + c8s;
  const u16* gB1 = Wp + (size_t)(bn * 128 + ca1 * 16 + r4) * 1024 + c8s;
  const int lo0 = ca0 * 512 + lane * 8;
  const int lo1 = ca1 * 512 + lane * 8;

  const int fr = lane & 15, quad = lane >> 4;
  int offA[4], offB[4];
  #pragma unroll
  for (int i = 0; i < 4; ++i){
    const int r = wm + i * 16 + fr;
    offA[i] = r * 32 + ((quad ^ ((r >> 1) & 3)) * 8);
  }
  #pragma unroll
  for (int j = 0; j < 4; ++j){
    const int r = wn + j * 16 + fr;
    offB[j] = r * 32 + ((quad ^ ((r >> 1) & 3)) * 8);
  }

#define STG(s, kk) \
    gload16(gA0 + (kk), &As[s][lo0]); \
    gload16(gA1 + (kk), &As[s][lo1]); \
    gload16(gB0 + (kk), &Bs[s][lo0]); \
    gload16(gB1 + (kk), &Bs[s][lo1]);

  STG(0, 0)
  STG(1, 32)
  asm volatile("s_waitcnt vmcnt(4)" ::: "memory");
  __builtin_amdgcn_sched_barrier(0);
  __builtin_amdgcn_s_barrier();
  asm volatile("" ::: "memory");
  __builtin_amdgcn_sched_barrier(0);

  int slot = 0;
  #pragma unroll 1
  for (int t = 0; t < 32; ++t){
    const int s2 = slot < 1 ? 2 : slot - 1;
    if (t < 30){ STG(s2, (t + 2) * 32) }
    const u16* as_ = As[slot];
    const u16* bs_ = Bs[slot];
    bf16x8 af[4], bfv[4];
    #pragma unroll
    for (int i = 0; i < 4; ++i) af[i]  = *(const bf16x8*)&as_[offA[i]];
    #pragma unroll
    for (int j = 0; j < 4; ++j) bfv[j] = *(const bf16x8*)&bs_[offB[j]];
    __builtin_amdgcn_s_setprio(1);
    #pragma unroll
    for (int i = 0; i < 4; ++i)
      #pragma unroll
      for (int j = 0; j < 4; ++j)
        acc[i][j] = __builtin_amdgcn_mfma_f32_16x16x32_bf16(af[i], bfv[j], acc[i][j], 0, 0, 0);
    __builtin_amdgcn_s_setprio(0);
    if (t < 30)       { asm volatile("s_waitcnt vmcnt(4)" ::: "memory"); }
    else if (t == 30) { asm volatile("s_waitcnt vmcnt(0)" ::: "memory"); }
    if (t < 31){
      __builtin_amdgcn_sched_barrier(0);
      __builtin_amdgcn_s_barrier();
      asm volatile("" ::: "memory");
      __builtin_amdgcn_sched_barrier(0);
    }
    slot = slot == 2 ? 0 : slot + 1;
  }
#undef STG

  // D layout: row = (lane>>4)*4 + r, col = lane&15 (m89-verified)
  #pragma unroll
  for (int i = 0; i < 4; ++i){
    #pragma unroll
    for (int j = 0; j < 4; ++j){
      const int gr0 = bm * 128 + wm + i * 16 + quad * 4;
      const int gc  = bn * 128 + wn + j * 16 + fr;
      const float bvv = bias[gc];
      if (MODE == 0 && wsel == 2){
        // V^T: [b][h][kk][s]; gr0%4==0 so 4 s-values pack into one 8B store
        const int b = gr0 >> 8, s0 = gr0 & 255, h = gc >> 6, kk = gc & 63;
        const u32 p0 = (u32)f2bf(acc[i][j][0] + bvv) |
                       ((u32)f2bf(acc[i][j][1] + bvv) << 16);
        const u32 p1 = (u32)f2bf(acc[i][j][2] + bvv) |
                       ((u32)f2bf(acc[i][j][3] + bvv) << 16);
        uint2 pk; pk.x = p0; pk.y = p1;
        *(uint2*)((u16*)outp + (size_t)2 * 8388608 + (size_t)b * 262144 +
                  (size_t)h * 16384 + (size_t)kk * 256 + s0) = pk;
      } else {
        #pragma unroll
        for (int r = 0; r < 4; ++r){
          const int gr = gr0 + r;
          const float val = (acc[i][j][r] + bvv) * scale;
          if (MODE == 0){
            const int b = gr >> 8, s = gr & 255, h = gc >> 6, kk = gc & 63;
            ((u16*)outp)[(size_t)wsel * 8388608 + (size_t)b * 262144 +
                         (size_t)h * 16384 + (size_t)s * 64 + kk] = f2bf(val);
          } else {
            ((float*)outp)[(size_t)gr * 1024 + gc] = val;
          }
        }
      }
    }
  }
}

// ---------------- MFMA attention: block per (b,h) --------------------------
// vT is (B,nh,dk,S) bf16 (written transposed by the QKV GEMM) -> PV B-frags
// read directly from global; no LDS V transpose, zero block barriers.
__global__ __launch_bounds__(256)
void attn_mfma(const u16* __restrict__ q, const u16* __restrict__ k,
               const u16* __restrict__ vT, const float* __restrict__ divp,
               u16* __restrict__ attn_s)
{
  __shared__ u16 Ps[4][16][136];
  const int bh = blockIdx.x;
  const int b = bh >> 4, h = bh & 15;
  const int tid = threadIdx.x, lane = tid & 63, w = tid >> 6;
  const int quad = lane >> 4, l15 = lane & 15;
  const u16* kh = k  + (size_t)bh * 16384;
  const u16* vh = vT + (size_t)bh * 16384;
  const u16* qh = q  + (size_t)bh * 16384;

  const f32x4 z = {0.f, 0.f, 0.f, 0.f};
  const int bp = 2 * h + (b >> 4);
  for (int i = 0; i < 4; ++i){
    const int row0 = w * 64 + i * 16;
    const bf16x8 af0 = *(const bf16x8*)(qh + (size_t)(row0 + l15) * 64 + quad * 8);
    const bf16x8 af1 = *(const bf16x8*)(qh + (size_t)(row0 + l15) * 64 + 32 + quad * 8);
    f32x4 sc[16];
    #pragma unroll
    for (int ct = 0; ct < 16; ++ct){
      const bf16x8 b0 = *(const bf16x8*)(kh + (size_t)(ct * 16 + l15) * 64 + quad * 8);
      const bf16x8 b1 = *(const bf16x8*)(kh + (size_t)(ct * 16 + l15) * 64 + 32 + quad * 8);
      f32x4 a = __builtin_amdgcn_mfma_f32_16x16x32_bf16(af0, b0, z, 0, 0, 0);
      sc[ct]  = __builtin_amdgcn_mfma_f32_16x16x32_bf16(af1, b1, a, 0, 0, 0);
    }
    if (w == 0){
      const float* dv = divp + (size_t)b * 4096 + (size_t)(i * 16 + quad * 4) * 64 + l15;
      #pragma unroll
      for (int ct = 0; ct < 4; ++ct)
        #pragma unroll
        for (int rr = 0; rr < 4; ++rr)
          sc[ct][rr] += dv[rr * 64 + ct * 16];
    }
    float rs[4];
    #pragma unroll
    for (int rr = 0; rr < 4; ++rr){
      float m = sc[0][rr];
      #pragma unroll
      for (int ct = 1; ct < 16; ++ct) m = fmaxf(m, sc[ct][rr]);
      #pragma unroll
      for (int o = 1; o < 16; o <<= 1) m = fmaxf(m, __shfl_xor(m, o, 64));
      float s = 0.f;
      #pragma unroll
      for (int ct = 0; ct < 16; ++ct){
        const float e = __expf(sc[ct][rr] - m); sc[ct][rr] = e; s += e;
      }
      #pragma unroll
      for (int o = 1; o < 16; o <<= 1) s += __shfl_xor(s, o, 64);
      rs[rr] = 1.f / s;
    }
    f32x4 o4[4] = {z, z, z, z};
    #pragma unroll
    for (int half = 0; half < 2; ++half){
      #pragma unroll
      for (int ct = 0; ct < 8; ++ct)
        #pragma unroll
        for (int rr = 0; rr < 4; ++rr)
          Ps[w][quad * 4 + rr][ct * 16 + l15] = f2bf(sc[half * 8 + ct][rr] * rs[rr]);
      #pragma unroll
      for (int kc = 0; kc < 4; ++kc){
        const bf16x8 pa = *(const bf16x8*)&Ps[w][l15][kc * 32 + quad * 8];
        #pragma unroll
        for (int nt = 0; nt < 4; ++nt){
          const bf16x8 vb8 = *(const bf16x8*)(vh + (size_t)(nt * 16 + l15) * 256 +
                                              half * 128 + kc * 32 + quad * 8);
          o4[nt] = __builtin_amdgcn_mfma_f32_16x16x32_bf16(pa, vb8, o4[nt], 0, 0, 0);
        }
      }
    }
    const int sp = (b & 15) * 16 + (w * 4 + i);
    #pragma unroll
    for (int nt = 0; nt < 4; ++nt)
      #pragma unroll
      for (int rr = 0; rr < 4; ++rr){
        const int slo = quad * 4 + rr;
        const int cp = slo * 64 + nt * 16 + l15;
        attn_s[((size_t)bp * 256 + sp) * 1024 + cp] = f2bf(o4[nt][rr]);
      }
  }
}

// ---------------- attention_weights: mean over heads -----------------------
// Wave-owns-heads: each wave processes 4 full heads (full 256-col rows ->
// softmax entirely in-wave, zero barriers in the h-loop), accumulates the
// head-mean in registers; single cross-wave LDS reduce at the end.
__global__ __launch_bounds__(256)
void aw_kernel(const u16* __restrict__ q, const u16* __restrict__ k,
               float* __restrict__ aw)
{
  __shared__ __align__(16) float awl[4][16][260];   // pad 260: 2-way (free) banks
  const int blk = blockIdx.x;
  const int b = blk >> 4, st = blk & 15;
  const int tid = threadIdx.x, lane = tid & 63, w = tid >> 6;
  const int quad = lane >> 4, l15 = lane & 15;
  const int rowb = st * 16;
  const f32x4 z = {0.f, 0.f, 0.f, 0.f};
  float awacc[16][4] = {};            // [ct][rr] partial mean over this wave's heads
  #pragma unroll 1
  for (int hi = 0; hi < 4; ++hi){
    const int h = hi * 4 + w;
    const u16* kh = k + (((size_t)b * 16 + h) * 16384);
    const u16* qh = q + (((size_t)b * 16 + h) * 16384);
    const bf16x8 af0 = *(const bf16x8*)(qh + (size_t)(rowb + l15) * 64 + quad * 8);
    const bf16x8 af1 = *(const bf16x8*)(qh + (size_t)(rowb + l15) * 64 + 32 + quad * 8);
    f32x4 sc[16];
    #pragma unroll
    for (int ct = 0; ct < 16; ++ct){
      const bf16x8 b0 = *(const bf16x8*)(kh + (size_t)(ct * 16 + l15) * 64 + quad * 8);
      const bf16x8 b1 = *(const bf16x8*)(kh + (size_t)(ct * 16 + l15) * 64 + 32 + quad * 8);
      f32x4 a = __builtin_amdgcn_mfma_f32_16x16x32_bf16(af0, b0, z, 0, 0, 0);
      sc[ct]  = __builtin_amdgcn_mfma_f32_16x16x32_bf16(af1, b1, a, 0, 0, 0);
    }
    #pragma unroll
    for (int rr = 0; rr < 4; ++rr){
      float m = sc[0][rr];
      #pragma unroll
      for (int ct = 1; ct < 16; ++ct) m = fmaxf(m, sc[ct][rr]);
      #pragma unroll
      for (int o = 1; o < 16; o <<= 1) m = fmaxf(m, __shfl_xor(m, o, 64));
      float s = 0.f;
      #pragma unroll
      for (int ct = 0; ct < 16; ++ct){
        const float e = __expf(sc[ct][rr] - m); sc[ct][rr] = e; s += e;
      }
      #pragma unroll
      for (int o = 1; o < 16; o <<= 1) s += __shfl_xor(s, o, 64);
      const float inv = 1.f / s;
      #pragma unroll
      for (int ct = 0; ct < 16; ++ct) awacc[ct][rr] += sc[ct][rr] * inv;
    }
  }
  // cross-wave reduce: each wave's awacc covers the full 16x256 tile
  #pragma unroll
  for (int ct = 0; ct < 16; ++ct)
    #pragma unroll
    for (int rr = 0; rr < 4; ++rr)
      awl[w][quad * 4 + rr][ct * 16 + l15] = awacc[ct][rr];
  __syncthreads();
  const size_t base = (size_t)b * 65536 + (size_t)rowb * 256;
  #pragma unroll
  for (int cc = 0; cc < 4; ++cc){
    const int idx = cc * 1024 + tid * 4;
    const int row = idx >> 8, col = idx & 255;
    const float4 a0 = *(const float4*)&awl[0][row][col];
    const float4 a1 = *(const float4*)&awl[1][row][col];
    const float4 a2 = *(const float4*)&awl[2][row][col];
    const float4 a3 = *(const float4*)&awl[3][row][col];
    float4 o;
    o.x = (a0.x + a1.x + a2.x + a3.x) * 0.0625f;
    o.y = (a0.y + a1.y + a2.y + a3.y) * 0.0625f;
    o.z = (a0.z + a1.z + a2.z + a3.z) * 0.0625f;
    o.w = (a0.w + a1.w + a2.w + a3.w) * 0.0625f;
    *(float4*)(aw + base + idx) = o;
  }
}

// ---------------- residual + layernorm epilogue (fp32) ---------------------
__global__ __launch_bounds__(256)
void ln_kernel(const float* __restrict__ y2, const float* __restrict__ x,
               const float* __restrict__ g, const float* __restrict__ bb,
               float* __restrict__ outp)
{
  __shared__ float red[4];
  const int r = blockIdx.x, tid = threadIdx.x;
  const float4 yv = ((const float4*)(y2 + (size_t)r * 1024))[tid];
  const float4 xv = ((const float4*)(x  + (size_t)r * 1024))[tid];
  const float v0 = yv.x + xv.x;
  const float v1 = yv.y + xv.y;
  const float v2 = yv.z + xv.z;
  const float v3 = yv.w + xv.w;
  const float ssum = blockRed(v0 + v1 + v2 + v3, 0, red, tid);
  const float mu = ssum * (1.f / 1024.f);
  const float d0 = v0 - mu, d1 = v1 - mu, d2 = v2 - mu, d3 = v3 - mu;
  const float sq = blockRed(d0 * d0 + d1 * d1 + d2 * d2 + d3 * d3, 0, red, tid);
  const float rstd = rsqrtf(sq * (1.f / 1024.f) + 1e-5f);
  const float4 gv = ((const float4*)g)[tid];
  const float4 bv = ((const float4*)bb)[tid];
  float4 o;
  o.x = d0 * rstd * gv.x + bv.x;
  o.y = d1 * rstd * gv.y + bv.y;
  o.z = d2 * rstd * gv.z + bv.z;
  o.w = d3 * rstd * gv.w + bv.w;
  ((float4*)(outp + (size_t)r * 1024))[tid] = o;
}

extern "C" void kernel_launch(void* const* d_in, const int* in_sizes, int n_in,
                              void* d_out, int out_size, void* d_ws, size_t ws_size,
                              hipStream_t stream)
{
  int ix = -1, ipf = -1, iw[4] = {-1,-1,-1,-1}, iv[6] = {-1,-1,-1,-1,-1,-1};
  int nw = 0, nv = 0;
  for (int i = 0; i < n_in; ++i){
    const int sz = in_sizes[i];
    if (sz == 8388608 && ix < 0) ix = i;
    else if (sz == 262144 && ipf < 0) ipf = i;
    else if (sz == 1048576 && nw < 4) iw[nw++] = i;
    else if (sz == 1024 && nv < 6) iv[nv++] = i;
  }
  if (ix < 0 || ipf < 0 || nw != 4 || nv != 6){
    ix = 0; ipf = 1; iw[0] = 2; iv[0] = 3; iw[1] = 4; iv[1] = 5;
    iw[2] = 6; iv[2] = 7; iw[3] = 8; iv[3] = 9; iv[4] = 10; iv[5] = 11;
  }

  const float* x   = (const float*)d_in[ix];
  const float* pf  = (const float*)d_in[ipf];
  const float* wq  = (const float*)d_in[iw[0]];
  const float* wk  = (const float*)d_in[iw[1]];
  const float* wv  = (const float*)d_in[iw[2]];
  const float* wo  = (const float*)d_in[iw[3]];
  const float* bq  = (const float*)d_in[iv[0]];
  const float* bk  = (const float*)d_in[iv[1]];
  const float* bv  = (const float*)d_in[iv[2]];
  const float* bo  = (const float*)d_in[iv[3]];
  const float* lng = (const float*)d_in[iv[4]];
  const float* lnb = (const float*)d_in[iv[5]];

  float* out0   = (float*)d_out;            // final (B,H,W,d) fp32
  float* aw_out = out0 + 8388608;           // (B,S,S) fp32

  // d_out staging (dead before ln_kernel writes out0):
  //   [0, 16.78M)      x_bf bf16 (consumed by QKV gemm)
  //   [16.78M, 33.55M) attn scrambled bf16 (consumed by out-proj gemm)
  u16* x_bf = (u16*)d_out;
  u16* attn = x_bf + 8388608;
  // ws: qkv bf16 [0,48M) (v region holds V^T); divp @48M (0.5M);
  // W bf16 arena @49M (8MB); y2 fp32 (32MB) aliases qkv after attention.
  u16* qkv    = (u16*)d_ws;
  float* divp = (float*)((char*)d_ws + (size_t)48 * 1048576);
  u16* warena = (u16*)((char*)d_ws + (size_t)49 * 1048576);
  float* y2   = (float*)d_ws;

  conv_all<<<6144, 256, 0, stream>>>(x, wq, wk, wv, wo, x_bf, warena);
  div_kernel<<<32, 256, 0, stream>>>(pf, divp);

  gemm_lds<0><<<dim3(64, 24), 256, 0, stream>>>(x_bf, warena, bq, bk, bv, (void*)qkv);

  u16* qw = qkv, *kw = qkv + 8388608, *vw = qkv + 16777216;
  attn_mfma<<<512, 256, 0, stream>>>(qw, kw, vw, divp, attn);
  aw_kernel<<<512, 256, 0, stream>>>(qw, kw, aw_out);

  gemm_lds<1><<<dim3(64, 8), 256, 0, stream>>>(attn, warena + 3145728, bo, nullptr, nullptr, (void*)y2);
  ln_kernel<<<8192, 256, 0, stream>>>(y2, x, lng, lnb, out0);
}

// Round 4
// 325.327 us; speedup vs baseline: 1.0876x; 1.0422x over previous
//
#include <hip/hip_runtime.h>

typedef unsigned short u16;
typedef unsigned int   u32;
typedef short bf16x8 __attribute__((ext_vector_type(8)));
typedef float f32x4  __attribute__((ext_vector_type(4)));

__device__ __forceinline__ float bf2f(u16 u){
  union { u32 u; float f; } c; c.u = ((u32)u) << 16; return c.f;
}
__device__ __forceinline__ u16 f2bf(float f){
  union { float f; u32 u; } c; c.f = f;
  u32 u = c.u + 0x7fffu + ((c.u >> 16) & 1u);
  return (u16)(u >> 16);
}

// async global->LDS, 16B per lane; LDS dest must be wave-uniform base + lane*16
__device__ __forceinline__ void gload16(const u16* g, u16* l){
  __builtin_amdgcn_global_load_lds((const __attribute__((address_space(1))) u32*)g,
                                   (__attribute__((address_space(3))) u32*)l, 16, 0, 0);
}

// ---------------- reductions ----------------------------------------------
__device__ __forceinline__ float waveRed(float v, int ismax){
  #pragma unroll
  for (int o = 32; o > 0; o >>= 1){
    float t = __shfl_xor(v, o, 64);
    v = ismax ? fmaxf(v, t) : (v + t);
  }
  return v;
}
__device__ __forceinline__ float blockRed(float v, int ismax, float* red, int tid){
  v = waveRed(v, ismax);
  __syncthreads();
  if ((tid & 63) == 0) red[tid >> 6] = v;
  __syncthreads();
  return ismax ? fmaxf(fmaxf(red[0], red[1]), fmaxf(red[2], red[3]))
               : (red[0] + red[1] + red[2] + red[3]);
}

// ---------------- fused fp32 -> bf16 converter (x + 4 weights) -------------
__global__ __launch_bounds__(256)
void conv_all(const float* __restrict__ x, const float* __restrict__ w0,
              const float* __restrict__ w1, const float* __restrict__ w2,
              const float* __restrict__ w3, u16* __restrict__ xdst,
              u16* __restrict__ wdst){
  const int bid = blockIdx.x;
  const float* s;
  u16* d;
  size_t i;
  if (bid < 4096){
    s = x; d = xdst;
    i = ((size_t)bid * 256 + threadIdx.x) * 8;
  } else {
    const int wb = bid - 4096;
    const int wi = wb >> 9;
    s = wi == 0 ? w0 : (wi == 1 ? w1 : (wi == 2 ? w2 : w3));
    d = wdst + (size_t)wi * 1048576;
    i = ((size_t)(wb & 511) * 256 + threadIdx.x) * 8;
  }
  const float4 a = *(const float4*)(s + i);
  const float4 b = *(const float4*)(s + i + 4);
  uint4 o;
  o.x = (u32)f2bf(a.x) | ((u32)f2bf(a.y) << 16);
  o.y = (u32)f2bf(a.z) | ((u32)f2bf(a.w) << 16);
  o.z = (u32)f2bf(b.x) | ((u32)f2bf(b.y) << 16);
  o.w = (u32)f2bf(b.z) | ((u32)f2bf(b.w) << 16);
  *(uint4*)(d + i) = o;
}

// ---------------- diversity bias table: divp[b][s][t] ----------------------
__global__ __launch_bounds__(256)
void div_kernel(const float* __restrict__ pf, float* __restrict__ divp)
{
  __shared__ float pfs[64][129];
  __shared__ float svs[64][65];
  const int b = blockIdx.x;
  const int tid = threadIdx.x;
  const float* pb = pf + (size_t)b * 8192;
  for (int i = tid; i < 8192; i += 256) pfs[i >> 7][i & 127] = pb[i];
  __syncthreads();
  const int p = tid & 63, qg = tid >> 6;
  for (int qq = qg * 16; qq < qg * 16 + 16; ++qq){
    float a = 0.f;
    #pragma unroll 8
    for (int f = 0; f < 128; ++f) a += pfs[p][f] * pfs[qq][f];
    svs[p][qq] = a;
  }
  __syncthreads();
  if (tid < 64){
    float m = -1e30f;
    for (int qq = 0; qq < 64; ++qq) m = fmaxf(m, svs[tid][qq]);
    float s = 0.f;
    for (int qq = 0; qq < 64; ++qq){ const float e = __expf(svs[tid][qq] - m); svs[tid][qq] = e; s += e; }
    const float inv = 1.f / s;
    float* dr = divp + ((size_t)b * 64 + tid) * 64;
    for (int qq = 0; qq < 64; ++qq) dr[qq] = 0.1f * (1.f - svs[tid][qq] * inv);
  }
}

// ---------------- 128x128 MFMA GEMM (round-1 verified pipeline) ------------
// Y = (A @ W^T + bias) * scale, bf16 K-contiguous (K=1024), BK=32.
// 3-slot rotating LDS, distance-2 prefetch, counted vmcnt(4), XOR swizzle.
// MODE 0: fused QKV (grid y 0..23, wsel=y>>3). Q,K scatter (B,nh,S,dk).
//   V (wsel==2) computes the TRANSPOSED GEMM (A-tiles = Wv rows, B-tiles = x
//   rows) so V^T (B,nh,dk,S) comes out with lane-consecutive (32B) stores —
//   same coalescing as Q/K; identical dot order -> bit-identical values.
// MODE 1: out-proj, fp32 row-major out.
template<int MODE>
__global__ __launch_bounds__(256, 3)
void gemm_lds(const u16* __restrict__ A, const u16* __restrict__ Wb,
              const float* __restrict__ bias0, const float* __restrict__ bias1,
              const float* __restrict__ bias2, void* __restrict__ outp)
{
  __shared__ u16 As[3][4096];
  __shared__ u16 Bs[3][4096];
  const int tid = threadIdx.x, lane = tid & 63, w = tid >> 6;
  const int wm = (w >> 1) * 64, wn = (w & 1) * 64;
  const int bm = blockIdx.x;
  int bn = blockIdx.y;
  const u16* Wp = Wb;
  const float* bias = bias0;
  float scale = 1.f;
  int wsel = 0;
  if (MODE == 0){
    wsel = bn >> 3; bn &= 7;
    Wp = Wb + (size_t)wsel * 1048576;
    bias = wsel == 0 ? bias0 : (wsel == 1 ? bias1 : bias2);
    if (wsel == 0) scale = 0.125f;      // fold 1/sqrt(dk) into Q
  }
  // tile roles: V-transposed GEMM swaps M-side to weight rows
  const bool vsw = (MODE == 0 && wsel == 2);
  const int mt  = vsw ? bn : bm;
  const int nt2 = vsw ? bm : bn;
  const u16* MA = vsw ? Wp : A;
  const u16* MB = vsw ? A  : Wp;

  const f32x4 z = {0.f, 0.f, 0.f, 0.f};
  f32x4 acc[4][4];
  #pragma unroll
  for (int i = 0; i < 4; ++i)
    #pragma unroll
    for (int j = 0; j < 4; ++j) acc[i][j] = z;

  const int r4  = lane >> 2;
  const int c8s = (((lane & 3) ^ ((lane >> 3) & 3)) * 8);
  const int ca0 = w * 2, ca1 = w * 2 + 1;
  const u16* gA0 = MA + (size_t)(mt  * 128 + ca0 * 16 + r4) * 1024 + c8s;
  const u16* gA1 = MA + (size_t)(mt  * 128 + ca1 * 16 + r4) * 1024 + c8s;
  const u16* gB0 = MB + (size_t)(nt2 * 128 + ca0 * 16 + r4) * 1024 + c8s;
  const u16* gB1 = MB + (size_t)(nt2 * 128 + ca1 * 16 + r4) * 1024 + c8s;
  const int lo0 = ca0 * 512 + lane * 8;
  const int lo1 = ca1 * 512 + lane * 8;

  const int fr = lane & 15, quad = lane >> 4;
  int offA[4], offB[4];
  #pragma unroll
  for (int i = 0; i < 4; ++i){
    const int r = wm + i * 16 + fr;
    offA[i] = r * 32 + ((quad ^ ((r >> 1) & 3)) * 8);
  }
  #pragma unroll
  for (int j = 0; j < 4; ++j){
    const int r = wn + j * 16 + fr;
    offB[j] = r * 32 + ((quad ^ ((r >> 1) & 3)) * 8);
  }

#define STG(s, kk) \
    gload16(gA0 + (kk), &As[s][lo0]); \
    gload16(gA1 + (kk), &As[s][lo1]); \
    gload16(gB0 + (kk), &Bs[s][lo0]); \
    gload16(gB1 + (kk), &Bs[s][lo1]);

  STG(0, 0)
  STG(1, 32)
  asm volatile("s_waitcnt vmcnt(4)" ::: "memory");
  __builtin_amdgcn_sched_barrier(0);
  __builtin_amdgcn_s_barrier();
  asm volatile("" ::: "memory");
  __builtin_amdgcn_sched_barrier(0);

  int slot = 0;
  #pragma unroll 1
  for (int t = 0; t < 32; ++t){
    const int s2 = slot < 1 ? 2 : slot - 1;
    if (t < 30){ STG(s2, (t + 2) * 32) }
    const u16* as_ = As[slot];
    const u16* bs_ = Bs[slot];
    bf16x8 af[4], bfv[4];
    #pragma unroll
    for (int i = 0; i < 4; ++i) af[i]  = *(const bf16x8*)&as_[offA[i]];
    #pragma unroll
    for (int j = 0; j < 4; ++j) bfv[j] = *(const bf16x8*)&bs_[offB[j]];
    __builtin_amdgcn_s_setprio(1);
    #pragma unroll
    for (int i = 0; i < 4; ++i)
      #pragma unroll
      for (int j = 0; j < 4; ++j)
        acc[i][j] = __builtin_amdgcn_mfma_f32_16x16x32_bf16(af[i], bfv[j], acc[i][j], 0, 0, 0);
    __builtin_amdgcn_s_setprio(0);
    if (t < 30)       { asm volatile("s_waitcnt vmcnt(4)" ::: "memory"); }
    else if (t == 30) { asm volatile("s_waitcnt vmcnt(0)" ::: "memory"); }
    if (t < 31){
      __builtin_amdgcn_sched_barrier(0);
      __builtin_amdgcn_s_barrier();
      asm volatile("" ::: "memory");
      __builtin_amdgcn_sched_barrier(0);
    }
    slot = slot == 2 ? 0 : slot + 1;
  }
#undef STG

  // D layout: row = (lane>>4)*4 + r, col = lane&15 (m89-verified)
  #pragma unroll
  for (int i = 0; i < 4; ++i){
    #pragma unroll
    for (int j = 0; j < 4; ++j){
      const int gr0 = mt  * 128 + wm + i * 16 + quad * 4;
      const int gc  = nt2 * 128 + wn + j * 16 + fr;
      if (vsw){
        // V^T: gr = weight row (h,kk), gc = (b,s); lanes -> consecutive s
        const int bb = gc >> 8, s = gc & 255;
        #pragma unroll
        for (int r = 0; r < 4; ++r){
          const int grow = gr0 + r;
          const int h = grow >> 6, kk = grow & 63;
          ((u16*)outp)[(size_t)2 * 8388608 + (size_t)bb * 262144 +
                       (size_t)h * 16384 + (size_t)kk * 256 + s] =
            f2bf(acc[i][j][r] + bias[grow]);
        }
      } else {
        const float bvv = bias[gc];
        #pragma unroll
        for (int r = 0; r < 4; ++r){
          const int gr = gr0 + r;
          const float val = (acc[i][j][r] + bvv) * scale;
          if (MODE == 0){
            const int b = gr >> 8, s = gr & 255, h = gc >> 6, kk = gc & 63;
            ((u16*)outp)[(size_t)wsel * 8388608 + (size_t)b * 262144 +
                         (size_t)h * 16384 + (size_t)s * 64 + kk] = f2bf(val);
          } else {
            ((float*)outp)[(size_t)gr * 1024 + gc] = val;
          }
        }
      }
    }
  }
}

// ---------------- fused attention + attention_weights ----------------------
// Block per (b, st): 16-row strip, 4 waves x 4 heads each (wave-owns-head).
// Raw pre-bias scores feed aw (mean over heads of unbiased softmax) for
// free; bias only touches rows<64 x cols<64, so only st<4 blocks run a dual
// softmax. PV reads V^T (B,nh,dk,S) fragments straight from global.
// XCD swizzle groups same-b blocks per XCD for K/V L2 locality.
__global__ __launch_bounds__(256, 2)
void attn_aw(const u16* __restrict__ q, const u16* __restrict__ k,
             const u16* __restrict__ vT, const float* __restrict__ divp,
             u16* __restrict__ attn_s, float* __restrict__ aw)
{
  __shared__ __align__(16) u16 Ps[4][16][136];   // per-wave P staging; reused as awl
  const int raw = blockIdx.x;
  const int blk = (raw & 7) * 64 + (raw >> 3);   // 512 blocks: bijective
  const int b = blk >> 4, st = blk & 15;
  const int tid = threadIdx.x, lane = tid & 63, w = tid >> 6;
  const int quad = lane >> 4, l15 = lane & 15;
  const int rowb = st * 16;
  const f32x4 z = {0.f, 0.f, 0.f, 0.f};
  float awacc[16][4] = {};      // unbiased softmax mean over this wave's heads

  #pragma unroll 1
  for (int hi = 0; hi < 4; ++hi){
    const int h = hi * 4 + w;
    const u16* qh = q  + ((size_t)b * 16 + h) * 16384;
    const u16* kh = k  + ((size_t)b * 16 + h) * 16384;
    const u16* vh = vT + ((size_t)b * 16 + h) * 16384;
    const bf16x8 af0 = *(const bf16x8*)(qh + (size_t)(rowb + l15) * 64 + quad * 8);
    const bf16x8 af1 = *(const bf16x8*)(qh + (size_t)(rowb + l15) * 64 + 32 + quad * 8);
    f32x4 sc[16];
    #pragma unroll
    for (int ct = 0; ct < 16; ++ct){
      const bf16x8 b0 = *(const bf16x8*)(kh + (size_t)(ct * 16 + l15) * 64 + quad * 8);
      const bf16x8 b1 = *(const bf16x8*)(kh + (size_t)(ct * 16 + l15) * 64 + 32 + quad * 8);
      f32x4 a = __builtin_amdgcn_mfma_f32_16x16x32_bf16(af0, b0, z, 0, 0, 0);
      sc[ct]  = __builtin_amdgcn_mfma_f32_16x16x32_bf16(af1, b1, a, 0, 0, 0);
    }
    float rs[4];
    if (st < 4){
      // unbiased softmax (aw path) -- keep sc raw
      #pragma unroll
      for (int rr = 0; rr < 4; ++rr){
        float m = sc[0][rr];
        #pragma unroll
        for (int ct = 1; ct < 16; ++ct) m = fmaxf(m, sc[ct][rr]);
        #pragma unroll
        for (int o = 1; o < 16; o <<= 1) m = fmaxf(m, __shfl_xor(m, o, 64));
        float s = 0.f;
        #pragma unroll
        for (int ct = 0; ct < 16; ++ct) s += __expf(sc[ct][rr] - m);
        #pragma unroll
        for (int o = 1; o < 16; o <<= 1) s += __shfl_xor(s, o, 64);
        const float inv = 1.f / s;
        #pragma unroll
        for (int ct = 0; ct < 16; ++ct)
          awacc[ct][rr] += __expf(sc[ct][rr] - m) * inv;
      }
      // add diversity bias (cols<64 -> ct<4), then biased softmax for attn
      const float* dv = divp + (size_t)b * 4096 + (size_t)(rowb + quad * 4) * 64 + l15;
      #pragma unroll
      for (int ct = 0; ct < 4; ++ct)
        #pragma unroll
        for (int rr = 0; rr < 4; ++rr)
          sc[ct][rr] += dv[rr * 64 + ct * 16];
      #pragma unroll
      for (int rr = 0; rr < 4; ++rr){
        float m = sc[0][rr];
        #pragma unroll
        for (int ct = 1; ct < 16; ++ct) m = fmaxf(m, sc[ct][rr]);
        #pragma unroll
        for (int o = 1; o < 16; o <<= 1) m = fmaxf(m, __shfl_xor(m, o, 64));
        float s = 0.f;
        #pragma unroll
        for (int ct = 0; ct < 16; ++ct){
          const float e = __expf(sc[ct][rr] - m); sc[ct][rr] = e; s += e;
        }
        #pragma unroll
        for (int o = 1; o < 16; o <<= 1) s += __shfl_xor(s, o, 64);
        rs[rr] = 1.f / s;
      }
    } else {
      // single softmax: biased == unbiased here
      #pragma unroll
      for (int rr = 0; rr < 4; ++rr){
        float m = sc[0][rr];
        #pragma unroll
        for (int ct = 1; ct < 16; ++ct) m = fmaxf(m, sc[ct][rr]);
        #pragma unroll
        for (int o = 1; o < 16; o <<= 1) m = fmaxf(m, __shfl_xor(m, o, 64));
        float s = 0.f;
        #pragma unroll
        for (int ct = 0; ct < 16; ++ct){
          const float e = __expf(sc[ct][rr] - m); sc[ct][rr] = e; s += e;
        }
        #pragma unroll
        for (int o = 1; o < 16; o <<= 1) s += __shfl_xor(s, o, 64);
        rs[rr] = 1.f / s;
        #pragma unroll
        for (int ct = 0; ct < 16; ++ct)
          awacc[ct][rr] += sc[ct][rr] * rs[rr];
      }
    }
    // PV: P(16x256) @ V(256x64) via V^T fragments from global
    f32x4 o4[4] = {z, z, z, z};
    #pragma unroll
    for (int half = 0; half < 2; ++half){
      #pragma unroll
      for (int ct = 0; ct < 8; ++ct)
        #pragma unroll
        for (int rr = 0; rr < 4; ++rr)
          Ps[w][quad * 4 + rr][ct * 16 + l15] = f2bf(sc[half * 8 + ct][rr] * rs[rr]);
      #pragma unroll
      for (int kc = 0; kc < 4; ++kc){
        const bf16x8 pa = *(const bf16x8*)&Ps[w][l15][kc * 32 + quad * 8];
        #pragma unroll
        for (int nt = 0; nt < 4; ++nt){
          const bf16x8 vb8 = *(const bf16x8*)(vh + (size_t)(nt * 16 + l15) * 256 +
                                              half * 128 + kc * 32 + quad * 8);
          o4[nt] = __builtin_amdgcn_mfma_f32_16x16x32_bf16(pa, vb8, o4[nt], 0, 0, 0);
        }
      }
    }
    // scramble scatter: row' = 512h + 16b + st, col' = (s&15)*64 + kk
    const size_t rbase = ((size_t)(512 * h + 16 * b + st)) * 1024;
    #pragma unroll
    for (int nt = 0; nt < 4; ++nt)
      #pragma unroll
      for (int rr = 0; rr < 4; ++rr)
        attn_s[rbase + (size_t)(quad * 4 + rr) * 64 + nt * 16 + l15] = f2bf(o4[nt][rr]);
  }

  // aw cross-wave reduce: reuse Ps as float [4][16][68] (17408B == sizeof Ps)
  float* awl = (float*)&Ps[0][0][0];
  const size_t base = (size_t)b * 65536 + (size_t)rowb * 256;
  #pragma unroll
  for (int cc = 0; cc < 4; ++cc){
    __syncthreads();
    #pragma unroll
    for (int j = 0; j < 4; ++j)
      #pragma unroll
      for (int rr = 0; rr < 4; ++rr)
        awl[(w * 16 + quad * 4 + rr) * 68 + j * 16 + l15] = awacc[cc * 4 + j][rr];
    __syncthreads();
    const int idx = tid * 4;
    const int row = idx >> 6, col = idx & 63;
    const float4 a0 = *(const float4*)&awl[(      row) * 68 + col];
    const float4 a1 = *(const float4*)&awl[(16  + row) * 68 + col];
    const float4 a2 = *(const float4*)&awl[(32  + row) * 68 + col];
    const float4 a3 = *(const float4*)&awl[(48  + row) * 68 + col];
    float4 o;
    o.x = (a0.x + a1.x + a2.x + a3.x) * 0.0625f;
    o.y = (a0.y + a1.y + a2.y + a3.y) * 0.0625f;
    o.z = (a0.z + a1.z + a2.z + a3.z) * 0.0625f;
    o.w = (a0.w + a1.w + a2.w + a3.w) * 0.0625f;
    *(float4*)(aw + base + (size_t)row * 256 + cc * 64 + col) = o;
  }
}

// ---------------- residual + layernorm epilogue (fp32) ---------------------
__global__ __launch_bounds__(256)
void ln_kernel(const float* __restrict__ y2, const float* __restrict__ x,
               const float* __restrict__ g, const float* __restrict__ bb,
               float* __restrict__ outp)
{
  __shared__ float red[4];
  const int r = blockIdx.x, tid = threadIdx.x;
  const float4 yv = ((const float4*)(y2 + (size_t)r * 1024))[tid];
  const float4 xv = ((const float4*)(x  + (size_t)r * 1024))[tid];
  const float v0 = yv.x + xv.x;
  const float v1 = yv.y + xv.y;
  const float v2 = yv.z + xv.z;
  const float v3 = yv.w + xv.w;
  const float ssum = blockRed(v0 + v1 + v2 + v3, 0, red, tid);
  const float mu = ssum * (1.f / 1024.f);
  const float d0 = v0 - mu, d1 = v1 - mu, d2 = v2 - mu, d3 = v3 - mu;
  const float sq = blockRed(d0 * d0 + d1 * d1 + d2 * d2 + d3 * d3, 0, red, tid);
  const float rstd = rsqrtf(sq * (1.f / 1024.f) + 1e-5f);
  const float4 gv = ((const float4*)g)[tid];
  const float4 bv = ((const float4*)bb)[tid];
  float4 o;
  o.x = d0 * rstd * gv.x + bv.x;
  o.y = d1 * rstd * gv.y + bv.y;
  o.z = d2 * rstd * gv.z + bv.z;
  o.w = d3 * rstd * gv.w + bv.w;
  ((float4*)(outp + (size_t)r * 1024))[tid] = o;
}

extern "C" void kernel_launch(void* const* d_in, const int* in_sizes, int n_in,
                              void* d_out, int out_size, void* d_ws, size_t ws_size,
                              hipStream_t stream)
{
  int ix = -1, ipf = -1, iw[4] = {-1,-1,-1,-1}, iv[6] = {-1,-1,-1,-1,-1,-1};
  int nw = 0, nv = 0;
  for (int i = 0; i < n_in; ++i){
    const int sz = in_sizes[i];
    if (sz == 8388608 && ix < 0) ix = i;
    else if (sz == 262144 && ipf < 0) ipf = i;
    else if (sz == 1048576 && nw < 4) iw[nw++] = i;
    else if (sz == 1024 && nv < 6) iv[nv++] = i;
  }
  if (ix < 0 || ipf < 0 || nw != 4 || nv != 6){
    ix = 0; ipf = 1; iw[0] = 2; iv[0] = 3; iw[1] = 4; iv[1] = 5;
    iw[2] = 6; iv[2] = 7; iw[3] = 8; iv[3] = 9; iv[4] = 10; iv[5] = 11;
  }

  const float* x   = (const float*)d_in[ix];
  const float* pf  = (const float*)d_in[ipf];
  const float* wq  = (const float*)d_in[iw[0]];
  const float* wk  = (const float*)d_in[iw[1]];
  const float* wv  = (const float*)d_in[iw[2]];
  const float* wo  = (const float*)d_in[iw[3]];
  const float* bq  = (const float*)d_in[iv[0]];
  const float* bk  = (const float*)d_in[iv[1]];
  const float* bv  = (const float*)d_in[iv[2]];
  const float* bo  = (const float*)d_in[iv[3]];
  const float* lng = (const float*)d_in[iv[4]];
  const float* lnb = (const float*)d_in[iv[5]];

  float* out0   = (float*)d_out;            // final (B,H,W,d) fp32
  float* aw_out = out0 + 8388608;           // (B,S,S) fp32

  // d_out staging (dead before ln_kernel writes out0):
  //   [0, 16.78M)      x_bf bf16 (consumed by QKV gemm)
  //   [16.78M, 33.55M) attn scrambled bf16 (consumed by out-proj gemm)
  u16* x_bf = (u16*)d_out;
  u16* attn = x_bf + 8388608;
  // ws: qkv bf16 [0,48M) (v region holds V^T); divp @48M (0.5M);
  // W bf16 arena @49M (8MB); y2 fp32 (32MB) aliases qkv after attention.
  u16* qkv    = (u16*)d_ws;
  float* divp = (float*)((char*)d_ws + (size_t)48 * 1048576);
  u16* warena = (u16*)((char*)d_ws + (size_t)49 * 1048576);
  float* y2   = (float*)d_ws;

  conv_all<<<6144, 256, 0, stream>>>(x, wq, wk, wv, wo, x_bf, warena);
  div_kernel<<<32, 256, 0, stream>>>(pf, divp);

  gemm_lds<0><<<dim3(64, 24), 256, 0, stream>>>(x_bf, warena, bq, bk, bv, (void*)qkv);

  u16* qw = qkv, *kw = qkv + 8388608, *vw = qkv + 16777216;
  attn_aw<<<512, 256, 0, stream>>>(qw, kw, vw, divp, attn, aw_out);

  gemm_lds<1><<<dim3(64, 8), 256, 0, stream>>>(attn, warena + 3145728, bo, nullptr, nullptr, (void*)y2);
  ln_kernel<<<8192, 256, 0, stream>>>(y2, x, lng, lnb, out0);
}